// Round 8
// baseline (240.197 us; speedup 1.0000x reference)
//
#include <hip/hip_runtime.h>
#include <hip/hip_bf16.h>

// Problem dims (fixed)
#define S_ 256
#define BSZ_ 64
#define IN_F_ 1024
#define OUT_F_ 512
#define USER_F_ 512

typedef short short8 __attribute__((ext_vector_type(8)));
typedef float f32x4 __attribute__((ext_vector_type(4)));

__device__ __forceinline__ ushort f2bf(float f) {
  unsigned u = __float_as_uint(f);
  unsigned r = (u + 0x7FFFu + ((u >> 16) & 1u)) >> 16;
  return (ushort)r;
}
__device__ __forceinline__ float bf2f(unsigned hi16) {
  return __uint_as_float(hi16 << 16);
}
// packed f32x2 -> bf16x2 (RNE, bit-identical to f2bf); v_cvt_pk_bf16_f32
__device__ __forceinline__ unsigned pkbf(float a, float b) {
  union { __hip_bfloat162 h; unsigned u; } x;
  x.h = __float22bfloat162_rn(float2{a, b});
  return x.u;
}
__device__ __forceinline__ float sigf(float x) {
  return 1.f / (1.f + __expf(-x));
}
__device__ __forceinline__ float tanh_safe(float x) {
  float ax = fabsf(x);
  float e = __expf(-2.f * ax);
  float r = (1.f - e) / (1.f + e);
  return copysignf(r, x);
}

// async global->LDS, 16B per lane; LDS dest = wave-uniform base + lane*16
__device__ __forceinline__ void gl_lds16(const void* g, void* l) {
  __builtin_amdgcn_global_load_lds(
      (const __attribute__((address_space(1))) void*)g,
      (__attribute__((address_space(3))) void*)l, 16, 0, 0);
}

// ---------------- prep: weight converts + logit zero (X stays fp32!) --------
// ranges (256-thread units): Wd vec4 [0,131072) | Wu vec4 [131072,196608)
// | W transpose scalar [196608,458752) | zero rowlog/collog vec4 [458752,466944)
__global__ void prep(const float* __restrict__ Wd, const float* __restrict__ Wu,
                     const float* __restrict__ W, float* __restrict__ rowlog,
                     ushort* __restrict__ Wd_bf, ushort* __restrict__ Wu_bf,
                     ushort* __restrict__ Wt_bf) {
  int i = blockIdx.x * 256 + threadIdx.x;
  if (i < 131072) {
    float4 v = ((const float4*)Wd)[i];
    ushort4 o; o.x = f2bf(v.x); o.y = f2bf(v.y); o.z = f2bf(v.z); o.w = f2bf(v.w);
    ((ushort4*)Wd_bf)[i] = o;
  } else if (i < 196608) {
    int j = i - 131072;
    float4 v = ((const float4*)Wu)[j];
    ushort4 o; o.x = f2bf(v.x); o.y = f2bf(v.y); o.z = f2bf(v.z); o.w = f2bf(v.w);
    ((ushort4*)Wu_bf)[j] = o;
  } else if (i < 458752) {
    int j = i - 196608;  // out index e*512+d -> W[d*512+e]
    Wt_bf[j] = f2bf(W[(j & 511) * 512 + (j >> 9)]);
  } else {
    int j = i - 458752;  // zero rowlog+collog (contiguous 32768 floats)
    ((float4*)rowlog)[j] = float4{0.f, 0.f, 0.f, 0.f};
  }
}

// ---------------- bf16 tile staging (R3/R5-proven) ----------------
// LDS row stride 64 shorts; 16B-chunk c of row r at phys slot c^(r&7).
template <int ROWS>
__device__ __forceinline__ void stage_tile(const ushort* __restrict__ g, int K,
                                           ushort* lds, int w, int lane) {
  const int rin = lane >> 3;  // 0..7
  const int c = lane & 7;     // 16B chunk slot within row
#pragma unroll
  for (int i = 0; i < ROWS / 32; ++i) {
    int r = w * (ROWS / 4) + i * 8 + rin;
    int gc = c ^ (r & 7);
    gl_lds16(g + (long)r * K + gc * 8, lds + w * (ROWS / 4) * 64 + i * 512);
  }
}
// ROWS=32 variant: one chunk per wave
__device__ __forceinline__ void stage_tile32(const ushort* __restrict__ g, int K,
                                             ushort* lds, int w, int lane) {
  const int rin = lane >> 3, c = lane & 7;
  int r = w * 8 + rin;
  int gc = c ^ (r & 7);
  gl_lds16(g + (long)r * K + gc * 8, lds + w * 512);
}

// fp32 A-tile staging: 64 rows x 64 f32 = 16KB. Row = 256B = 16 chunks of 16B;
// phys chunk pc = (c&8) | ((c&7)^(r&7)). Lane L of chunk i: row w*16+i*4+(L>>4),
// chunk slot L&15 -> LDS offset (L>>4)*256 + (L&15)*16 = L*16 (lane-contiguous ✓).
__device__ __forceinline__ void stage_a32(const float* __restrict__ g, int K,
                                          float* lds, int w, int lane) {
  const int rl = lane >> 4;   // 0..3
  const int c = lane & 15;    // 16B chunk slot within row
#pragma unroll
  for (int i = 0; i < 4; ++i) {
    int r = w * 16 + i * 4 + rl;
    int gc = (c & 8) | ((c & 7) ^ (r & 7));
    gl_lds16(g + (long)r * K + gc * 4, lds + w * 1024 + i * 256);
  }
}

__device__ __forceinline__ short8 frag(const ushort* lds, int row, int kk, int q) {
  int pc = (kk * 4 + q) ^ (row & 7);
  return *(const short8*)(lds + row * 64 + pc * 8);
}
// t_lds variant: row stride 512 shorts, K-window k (64 cols each)
__device__ __forceinline__ short8 frag512(const ushort* lds, int row, int k,
                                          int kk, int q) {
  int pc = (kk * 4 + q) ^ (row & 7);
  return *(const short8*)(lds + row * 512 + k * 64 + pc * 8);
}
// fp32 A-frag: read 2x b128 fp32, packed-cvt to bf16 (RNE). Bank-balanced:
// per b128 wave-op each of 8 bank-groups serves exactly 8 lanes.
__device__ __forceinline__ short8 fragA32(const float* lds, int row, int kk, int q) {
  int kc = kk * 4 + q;               // bf16-equivalent 16B chunk 0..7
  int f0 = kc * 2, f1 = kc * 2 + 1;  // fp32 16B chunks 0..15
  int p0 = (f0 & 8) | ((f0 & 7) ^ (row & 7));
  int p1 = (f1 & 8) | ((f1 & 7) ^ (row & 7));
  const f32x4* base = (const f32x4*)(lds + row * 64);
  f32x4 a = base[p0], b = base[p1];
  union { short8 s; uint4 u; } o;
  o.u.x = pkbf(a[0], a[1]); o.u.y = pkbf(a[2], a[3]);
  o.u.z = pkbf(b[0], b[1]); o.u.w = pkbf(b[2], b[3]);
  return o.s;
}

// BM=64 x BN=128, 4 waves as 2x2 (wave tile 32x64): acc[2][4]
__device__ __forceinline__ void compute_step(const ushort* As, const ushort* Bs,
                                             f32x4 acc[2][4], int wr, int wc,
                                             int mlane, int q) {
#pragma unroll
  for (int kk = 0; kk < 2; ++kk) {
    short8 af[2], bfr[4];
#pragma unroll
    for (int r = 0; r < 2; ++r) af[r] = frag(As, wr * 32 + r * 16 + mlane, kk, q);
#pragma unroll
    for (int c = 0; c < 4; ++c) bfr[c] = frag(Bs, wc * 64 + c * 16 + mlane, kk, q);
#pragma unroll
    for (int r = 0; r < 2; ++r)
#pragma unroll
      for (int c = 0; c < 4; ++c)
        acc[r][c] = __builtin_amdgcn_mfma_f32_16x16x32_bf16(af[r], bfr[c], acc[r][c], 0, 0, 0);
  }
}
// same, A from fp32 LDS
__device__ __forceinline__ void compute_step_f32(const float* Asf, const ushort* Bs,
                                                 f32x4 acc[2][4], int wr, int wc,
                                                 int mlane, int q) {
#pragma unroll
  for (int kk = 0; kk < 2; ++kk) {
    short8 af[2], bfr[4];
#pragma unroll
    for (int r = 0; r < 2; ++r) af[r] = fragA32(Asf, wr * 32 + r * 16 + mlane, kk, q);
#pragma unroll
    for (int c = 0; c < 4; ++c) bfr[c] = frag(Bs, wc * 64 + c * 16 + mlane, kk, q);
#pragma unroll
    for (int r = 0; r < 2; ++r)
#pragma unroll
      for (int c = 0; c < 4; ++c)
        acc[r][c] = __builtin_amdgcn_mfma_f32_16x16x32_bf16(af[r], bfr[c], acc[r][c], 0, 0, 0);
  }
}

// K-loop, all-bf16 (R5-proven)
template <int NSTEP>
__device__ __forceinline__ void gemm_loop(const ushort* __restrict__ A,
                                          const ushort* __restrict__ B, int K,
                                          ushort* As, ushort* Bs, f32x4 acc[2][4],
                                          int w, int lane, int wr, int wc,
                                          int mlane, int q) {
#pragma unroll 1
  for (int k = 0; k < NSTEP; ++k) {
    stage_tile<64>(A + k * 64, K, As, w, lane);
    stage_tile<128>(B + k * 64, K, Bs, w, lane);
    __syncthreads();
    compute_step(As, Bs, acc, wr, wc, mlane, q);
    __syncthreads();
  }
}
// K-loop, A fp32 via async staging (fused convert in the frag path)
template <int NSTEP>
__device__ __forceinline__ void gemm_loop_f32(const float* __restrict__ Af,
                                              const ushort* __restrict__ B, int K,
                                              float* Asf, ushort* Bs,
                                              f32x4 acc[2][4], int w, int lane,
                                              int wr, int wc, int mlane, int q) {
#pragma unroll 1
  for (int k = 0; k < NSTEP; ++k) {
    stage_a32(Af + k * 64, K, Asf, w, lane);
    stage_tile<128>(B + k * 64, K, Bs, w, lane);
    __syncthreads();
    compute_step_f32(Asf, Bs, acc, wr, wc, mlane, q);
    __syncthreads();
  }
}

#define ACC_ZERO(a)                             \
  _Pragma("unroll") for (int r = 0; r < 2; ++r) \
  _Pragma("unroll") for (int c = 0; c < 4; ++c) { \
    a[r][c][0] = 0.f; a[r][c][1] = 0.f; a[r][c][2] = 0.f; a[r][c][3] = 0.f; }

// ---------------- fused convert + d/u GEMM + gating ----------------
__global__ __launch_bounds__(256, 4) void gemm_du(
    const float* __restrict__ Xd, const ushort* __restrict__ Wd,
    const float* __restrict__ bd,
    const float* __restrict__ Xu, const ushort* __restrict__ Wu,
    const float* __restrict__ bu,
    ushort* __restrict__ dg, ushort* __restrict__ ug) {
  __shared__ ushort sm[16384];  // 32KB: Asf fp32 64x64 (16KB) + Bs 128x64 (16KB)
  float* Asf = (float*)sm;      // 4096 floats
  ushort* Bs = sm + 8192;
  const int i = blockIdx.x;
  const int k8 = i & 7, j = i >> 3;           // j in [0,128)
  const int by = k8 * 32 + (j >> 2), bx = j & 3;
  const int tid = threadIdx.x, lane = tid & 63, w = tid >> 6;
  const int wr = w >> 1, wc = w & 1, mlane = lane & 15, q = lane >> 4;
  const int m0 = by * 64, n0 = bx * 128;

  f32x4 accd[2][4]; ACC_ZERO(accd);
  gemm_loop_f32<16>(Xd + (long)m0 * 1024, Wd + (long)n0 * 1024, 1024,
                    Asf, Bs, accd, w, lane, wr, wc, mlane, q);
  f32x4 accu[2][4]; ACC_ZERO(accu);
  gemm_loop_f32<8>(Xu + (long)m0 * 512, Wu + (long)n0 * 512, 512,
                   Asf, Bs, accu, w, lane, wr, wc, mlane, q);

#pragma unroll
  for (int c = 0; c < 4; ++c) {
    const int gn = n0 + wc * 64 + c * 16 + mlane;
    const float bdv = bd[gn], buv = bu[gn];
#pragma unroll
    for (int r = 0; r < 2; ++r)
#pragma unroll
      for (int ii = 0; ii < 4; ++ii) {
        const int gm = m0 + wr * 32 + r * 16 + q * 4 + ii;
        const long idx = (long)gm * OUT_F_ + gn;
        float dp = accd[r][c][ii] + bdv;
        float up = accu[r][c][ii] + buv;
        float dgv = dp * sigf(up);
        float ugv = up * sigf(dgv);
        dg[idx] = f2bf(dgv);
        ug[idx] = f2bf(ugv);
      }
  }
}

// ---------------- fused t-GEMM + att-GEMM + tanh + reductions ----------------
__global__ __launch_bounds__(256, 2) void gemm_tatt(
    const ushort* __restrict__ dg, const ushort* __restrict__ Wt,
    const ushort* __restrict__ ug, float* __restrict__ rowlog,
    float* __restrict__ collog) {
  __shared__ ushort sm[32768];  // 64KB
  ushort* t_lds = sm;           // [32][512] shorts = 32KB
  ushort* AsT = sm + 16384;     // t-phase A stage: 32x64 = 4KB
  ushort* BsT = sm + 18432;     // t-phase B stage: 128x64 = 16KB
  ushort* BsU = sm + 16384;     // att-phase B stage: 256x64 = 32KB (aliases)
  const int i = blockIdx.x;
  const int xcd = i & 7, j = i >> 3;   // j in [0,64)
  const int b = xcd * 8 + (j >> 3);    // batch; 8 blocks of b share one XCD L2
  const int by = j & 7;                // 32-row s-strip
  const int tid = threadIdx.x, lane = tid & 63, w = tid >> 6;
  const int mlane = lane & 15, q = lane >> 4;
  const ushort* dgs = dg + (long)b * (S_ * OUT_F_) + (long)by * 32 * 512;
  const ushort* ugb = ug + (long)b * (S_ * OUT_F_);

  // ---- phase 1: t strip (waves 1x4 over cols)
#pragma unroll 1
  for (int nc = 0; nc < 4; ++nc) {
    f32x4 acc[2][2];
#pragma unroll
    for (int r = 0; r < 2; ++r)
#pragma unroll
      for (int c = 0; c < 2; ++c) {
        acc[r][c][0] = 0.f; acc[r][c][1] = 0.f; acc[r][c][2] = 0.f; acc[r][c][3] = 0.f;
      }
    const ushort* Bw = Wt + (long)(nc * 128) * 512;
#pragma unroll 1
    for (int k = 0; k < 8; ++k) {
      stage_tile32(dgs + k * 64, 512, AsT, w, lane);
      stage_tile<128>(Bw + k * 64, 512, BsT, w, lane);
      __syncthreads();
#pragma unroll
      for (int kk = 0; kk < 2; ++kk) {
        short8 af[2], bfr[2];
#pragma unroll
        for (int r = 0; r < 2; ++r) af[r] = frag(AsT, r * 16 + mlane, kk, q);
#pragma unroll
        for (int c = 0; c < 2; ++c)
          bfr[c] = frag(BsT, w * 32 + c * 16 + mlane, kk, q);
#pragma unroll
        for (int r = 0; r < 2; ++r)
#pragma unroll
          for (int c = 0; c < 2; ++c)
            acc[r][c] = __builtin_amdgcn_mfma_f32_16x16x32_bf16(af[r], bfr[c], acc[r][c], 0, 0, 0);
      }
      __syncthreads();
    }
#pragma unroll
    for (int r = 0; r < 2; ++r)
#pragma unroll
      for (int c = 0; c < 2; ++c)
#pragma unroll
        for (int ii = 0; ii < 4; ++ii) {
          int rr = r * 16 + q * 4 + ii;
          int col = nc * 128 + w * 32 + c * 16 + mlane;
          int cc = col >> 3;
          int ph = (cc & ~7) | ((cc & 7) ^ (rr & 7));
          t_lds[rr * 512 + ph * 8 + (col & 7)] = f2bf(acc[r][c][ii]);
        }
  }

  // ---- phase 2: att = t . ug^T (waves 1x4 over r-cols)
  f32x4 acc[2][4]; ACC_ZERO(acc);
#pragma unroll 1
  for (int k = 0; k < 8; ++k) {
    stage_tile<256>(ugb + k * 64, 512, BsU, w, lane);
    __syncthreads();
#pragma unroll
    for (int kk = 0; kk < 2; ++kk) {
      short8 af[2], bfr[4];
#pragma unroll
      for (int r = 0; r < 2; ++r) af[r] = frag512(t_lds, r * 16 + mlane, k, kk, q);
#pragma unroll
      for (int c = 0; c < 4; ++c)
        bfr[c] = frag(BsU, w * 64 + c * 16 + mlane, kk, q);
#pragma unroll
      for (int r = 0; r < 2; ++r)
#pragma unroll
        for (int c = 0; c < 4; ++c)
          acc[r][c] = __builtin_amdgcn_mfma_f32_16x16x32_bf16(af[r], bfr[c], acc[r][c], 0, 0, 0);
    }
    __syncthreads();
  }

  float rs[8], cs[4];
#pragma unroll
  for (int x = 0; x < 8; ++x) rs[x] = 0.f;
#pragma unroll
  for (int c = 0; c < 4; ++c) cs[c] = 0.f;
#pragma unroll
  for (int r = 0; r < 2; ++r)
#pragma unroll
    for (int c = 0; c < 4; ++c)
#pragma unroll
      for (int ii = 0; ii < 4; ++ii) {
        float v = tanh_safe(acc[r][c][ii]);
        rs[r * 4 + ii] += v;
        cs[c] += v;
      }
#pragma unroll
  for (int m = 1; m < 16; m <<= 1)
#pragma unroll
    for (int x = 0; x < 8; ++x) rs[x] += __shfl_xor(rs[x], m, 64);
#pragma unroll
  for (int m = 16; m < 64; m <<= 1)
#pragma unroll
    for (int c = 0; c < 4; ++c) cs[c] += __shfl_xor(cs[c], m, 64);

  float* rsum = (float*)BsU;
  if (tid < 32) rsum[tid] = 0.f;
  __syncthreads();
  if (mlane == 0) {
#pragma unroll
    for (int x = 0; x < 8; ++x)
      atomicAdd(&rsum[(x >> 2) * 16 + q * 4 + (x & 3)], rs[x]);
  }
  if (q == 0) {
#pragma unroll
    for (int c = 0; c < 4; ++c)
      atomicAdd(&collog[b * S_ + w * 64 + c * 16 + mlane], cs[c]);
  }
  __syncthreads();
  if (tid < 32) rowlog[b * S_ + by * 32 + tid] = rsum[tid];
}

// ---------------- finalize: softmax + weighted sums -------------------------
__device__ __forceinline__ float block_max(float v, float* buf, int tid) {
  buf[tid] = v; __syncthreads();
  for (int s = 128; s > 0; s >>= 1) {
    if (tid < s) buf[tid] = fmaxf(buf[tid], buf[tid + s]);
    __syncthreads();
  }
  float r = buf[0]; __syncthreads();
  return r;
}
__device__ __forceinline__ float block_sum(float v, float* buf, int tid) {
  buf[tid] = v; __syncthreads();
  for (int s = 128; s > 0; s >>= 1) {
    if (tid < s) buf[tid] = buf[tid] + buf[tid + s];
    __syncthreads();
  }
  float r = buf[0]; __syncthreads();
  return r;
}

__global__ __launch_bounds__(256) void finalize(
    const float* __restrict__ rowlog, const float* __restrict__ collog,
    const ushort* __restrict__ dg, const ushort* __restrict__ ug,
    float* __restrict__ out) {
  __shared__ float sd[S_], su[S_], buf[S_];
  const int b = blockIdx.x >> 1, half = blockIdx.x & 1;
  const int tid = threadIdx.x;

  const float rowmean = rowlog[b * S_ + tid] * (1.f / (float)S_);
  const float colmean = collog[b * S_ + tid] * (1.f / (float)S_);

  float md = block_max(rowmean, buf, tid);
  float ed = __expf(rowmean - md);
  float sds = block_sum(ed, buf, tid);
  sd[tid] = ed / sds;
  float mu = block_max(colmean, buf, tid);
  float eu = __expf(colmean - mu);
  float sus = block_sum(eu, buf, tid);
  su[tid] = eu / sus;
  __syncthreads();

  const int arr = tid >> 7;
  const int o = half * 256 + (tid & 127) * 2;
  const ushort* src = arr ? ug : dg;
  const float* sw = arr ? su : sd;
  const ushort* p = src + (long)b * (S_ * OUT_F_) + o;
  float a0 = 0.f, a1 = 0.f;
#pragma unroll 4
  for (int s = 0; s < S_; ++s) {
    ushort2 v = *(const ushort2*)(p + (long)s * OUT_F_);
    a0 += sw[s] * bf2f(v.x);
    a1 += sw[s] * bf2f(v.y);
  }
  float* ob = out + (arr ? BSZ_ * OUT_F_ : 0) + b * OUT_F_ + o;
  ob[0] = a0; ob[1] = a1;
}

extern "C" void kernel_launch(void* const* d_in, const int* in_sizes, int n_in,
                              void* d_out, int out_size, void* d_ws, size_t ws_size,
                              hipStream_t stream) {
  (void)in_sizes; (void)n_in; (void)out_size; (void)ws_size;
  const float* Xd = (const float*)d_in[0];
  const float* Xu = (const float*)d_in[1];
  const float* Wd = (const float*)d_in[2];
  const float* bd = (const float*)d_in[3];
  const float* Wu = (const float*)d_in[4];
  const float* bu = (const float*)d_in[5];
  const float* W  = (const float*)d_in[6];
  float* out = (float*)d_out;
  char* ws = (char*)d_ws;

  ushort* Wd_bf  = (ushort*)(ws + 0L);          //  1,048,576
  ushort* Wu_bf  = (ushort*)(ws + 1048576L);    //    524,288
  ushort* Wt_bf  = (ushort*)(ws + 1572864L);    //    524,288
  ushort* dg     = (ushort*)(ws + 2097152L);    // 16,777,216
  ushort* ug     = (ushort*)(ws + 18874368L);   // 16,777,216
  float*  rowlog = (float*)(ws + 35651584L);    //     65,536
  float*  collog = (float*)(ws + 35717120L);    //     65,536 (contiguous)

  prep<<<1824, 256, 0, stream>>>(Wd, Wu, W, rowlog, Wd_bf, Wu_bf, Wt_bf);

  dim3 blk(256);
  gemm_du<<<1024, blk, 0, stream>>>(Xd, Wd_bf, bd, Xu, Wu_bf, bu, dg, ug);
  gemm_tatt<<<512, blk, 0, stream>>>(dg, Wt_bf, ug, rowlog, collog);
  finalize<<<128, 256, 0, stream>>>(rowlog, collog, dg, ug, out);
}

// Round 9
// 231.369 us; speedup vs baseline: 1.0382x; 1.0382x over previous
//
#include <hip/hip_runtime.h>
#include <hip/hip_bf16.h>

// Problem dims (fixed)
#define S_ 256
#define BSZ_ 64
#define IN_F_ 1024
#define OUT_F_ 512
#define USER_F_ 512

typedef short short8 __attribute__((ext_vector_type(8)));
typedef float f32x4 __attribute__((ext_vector_type(4)));

__device__ __forceinline__ ushort f2bf(float f) {
  unsigned u = __float_as_uint(f);
  unsigned r = (u + 0x7FFFu + ((u >> 16) & 1u)) >> 16;
  return (ushort)r;
}
__device__ __forceinline__ float bf2f(unsigned hi16) {
  return __uint_as_float(hi16 << 16);
}
__device__ __forceinline__ float sigf(float x) {
  return 1.f / (1.f + __expf(-x));
}
__device__ __forceinline__ float tanh_safe(float x) {
  float ax = fabsf(x);
  float e = __expf(-2.f * ax);
  float r = (1.f - e) / (1.f + e);
  return copysignf(r, x);
}

// async global->LDS, 16B per lane; LDS dest = wave-uniform base + lane*16
__device__ __forceinline__ void gl_lds16(const ushort* g, ushort* l) {
  __builtin_amdgcn_global_load_lds(
      (const __attribute__((address_space(1))) void*)g,
      (__attribute__((address_space(3))) void*)l, 16, 0, 0);
}

// ---------------- prep: ALL converts + logit zero in ONE kernel (R7) --------
__global__ void prep(const float* __restrict__ Xd, const float* __restrict__ Xu,
                     const float* __restrict__ Wd, const float* __restrict__ Wu,
                     const float* __restrict__ W,
                     ushort* __restrict__ Xd_bf, ushort* __restrict__ Xu_bf,
                     ushort* __restrict__ Wd_bf, ushort* __restrict__ Wu_bf,
                     ushort* __restrict__ Wt_bf, float* __restrict__ rowlog) {
  int i = blockIdx.x * 256 + threadIdx.x;
  if (i < 4194304) {
    float4 v = ((const float4*)Xd)[i];
    ushort4 o; o.x = f2bf(v.x); o.y = f2bf(v.y); o.z = f2bf(v.z); o.w = f2bf(v.w);
    ((ushort4*)Xd_bf)[i] = o;
  } else if (i < 6291456) {
    int j = i - 4194304;
    float4 v = ((const float4*)Xu)[j];
    ushort4 o; o.x = f2bf(v.x); o.y = f2bf(v.y); o.z = f2bf(v.z); o.w = f2bf(v.w);
    ((ushort4*)Xu_bf)[j] = o;
  } else if (i < 6422528) {
    int j = i - 6291456;
    float4 v = ((const float4*)Wd)[j];
    ushort4 o; o.x = f2bf(v.x); o.y = f2bf(v.y); o.z = f2bf(v.z); o.w = f2bf(v.w);
    ((ushort4*)Wd_bf)[j] = o;
  } else if (i < 6488064) {
    int j = i - 6422528;
    float4 v = ((const float4*)Wu)[j];
    ushort4 o; o.x = f2bf(v.x); o.y = f2bf(v.y); o.z = f2bf(v.z); o.w = f2bf(v.w);
    ((ushort4*)Wu_bf)[j] = o;
  } else if (i < 6750208) {
    int j = i - 6488064;  // out index e*512+d -> W[d*512+e]
    Wt_bf[j] = f2bf(W[(j & 511) * 512 + (j >> 9)]);
  } else {
    int j = i - 6750208;  // zero rowlog+collog (contiguous 32768 floats)
    ((float4*)rowlog)[j] = float4{0.f, 0.f, 0.f, 0.f};
  }
}

// ---------------- bf16 tile staging (R3/R5-proven) ----------------
// LDS row stride 64 shorts; 16B-chunk c of row r at phys slot c^(r&7).
template <int ROWS>
__device__ __forceinline__ void stage_tile(const ushort* __restrict__ g, int K,
                                           ushort* lds, int w, int lane) {
  const int rin = lane >> 3;  // 0..7
  const int c = lane & 7;     // 16B chunk slot within row
#pragma unroll
  for (int i = 0; i < ROWS / 32; ++i) {
    int r = w * (ROWS / 4) + i * 8 + rin;
    int gc = c ^ (r & 7);
    gl_lds16(g + (long)r * K + gc * 8, lds + w * (ROWS / 4) * 64 + i * 512);
  }
}
// ROWS=32 variant: one chunk per wave
__device__ __forceinline__ void stage_tile32(const ushort* __restrict__ g, int K,
                                             ushort* lds, int w, int lane) {
  const int rin = lane >> 3, c = lane & 7;
  int r = w * 8 + rin;
  int gc = c ^ (r & 7);
  gl_lds16(g + (long)r * K + gc * 8, lds + w * 512);
}

__device__ __forceinline__ short8 frag(const ushort* lds, int row, int kk, int q) {
  int pc = (kk * 4 + q) ^ (row & 7);
  return *(const short8*)(lds + row * 64 + pc * 8);
}
// t_lds variant: row stride 512 shorts, K-window k (64 cols each)
__device__ __forceinline__ short8 frag512(const ushort* lds, int row, int k,
                                          int kk, int q) {
  int pc = (kk * 4 + q) ^ (row & 7);
  return *(const short8*)(lds + row * 512 + k * 64 + pc * 8);
}

// ---------------- gemm_du: 64x64 tile, 4 waves 2x2 (wave-tile 32x32) --------
// acc[2][2] (16 AGPR each for d/u) -> ~88 total regs -> 5 waves/SIMD resident
// (512-reg/SIMD pool), vs 120 regs / 4 waves at the old 64x128 tile. The
// K-step is latency-bound (L2-BW floor ~18 us vs 41.5 measured); +25% waves.
template <int NSTEP>
__device__ __forceinline__ void gemm_loop64(const ushort* __restrict__ A,
                                            const ushort* __restrict__ B, int K,
                                            ushort* As, ushort* Bs, f32x4 acc[2][2],
                                            int w, int lane, int wr, int wc,
                                            int mlane, int q) {
#pragma unroll 1
  for (int k = 0; k < NSTEP; ++k) {
    stage_tile<64>(A + k * 64, K, As, w, lane);
    stage_tile<64>(B + k * 64, K, Bs, w, lane);
    __syncthreads();
#pragma unroll
    for (int kk = 0; kk < 2; ++kk) {
      short8 af[2], bfr[2];
#pragma unroll
      for (int r = 0; r < 2; ++r) af[r] = frag(As, wr * 32 + r * 16 + mlane, kk, q);
#pragma unroll
      for (int c = 0; c < 2; ++c) bfr[c] = frag(Bs, wc * 32 + c * 16 + mlane, kk, q);
#pragma unroll
      for (int r = 0; r < 2; ++r)
#pragma unroll
        for (int c = 0; c < 2; ++c)
          acc[r][c] = __builtin_amdgcn_mfma_f32_16x16x32_bf16(af[r], bfr[c], acc[r][c], 0, 0, 0);
    }
    __syncthreads();
  }
}

#define ACC_ZERO22(a)                           \
  _Pragma("unroll") for (int r = 0; r < 2; ++r) \
  _Pragma("unroll") for (int c = 0; c < 2; ++c) { \
    a[r][c][0] = 0.f; a[r][c][1] = 0.f; a[r][c][2] = 0.f; a[r][c][3] = 0.f; }

// grid 2048 flat. XCD swizzle: i&7 = XCD; the 8 x-blocks sharing an A-strip
// are consecutive j on one XCD -> A-strip served from that XCD's L2.
__global__ __launch_bounds__(256, 5) void gemm_du(
    const ushort* __restrict__ Xd, const ushort* __restrict__ Wd,
    const float* __restrict__ bd,
    const ushort* __restrict__ Xu, const ushort* __restrict__ Wu,
    const float* __restrict__ bu,
    ushort* __restrict__ dg, ushort* __restrict__ ug) {
  __shared__ ushort sm[8192];  // 16KB: As 64x64 + Bs 64x64
  ushort* As = sm; ushort* Bs = sm + 4096;
  const int i = blockIdx.x;
  const int xcd = i & 7, j = i >> 3;           // j in [0,256)
  const int by = xcd * 32 + (j >> 3), bx = j & 7;
  const int tid = threadIdx.x, lane = tid & 63, w = tid >> 6;
  const int wr = w >> 1, wc = w & 1, mlane = lane & 15, q = lane >> 4;
  const int m0 = by * 64, n0 = bx * 64;

  f32x4 accd[2][2]; ACC_ZERO22(accd);
  gemm_loop64<16>(Xd + (long)m0 * 1024, Wd + (long)n0 * 1024, 1024,
                  As, Bs, accd, w, lane, wr, wc, mlane, q);
  f32x4 accu[2][2]; ACC_ZERO22(accu);
  gemm_loop64<8>(Xu + (long)m0 * 512, Wu + (long)n0 * 512, 512,
                 As, Bs, accu, w, lane, wr, wc, mlane, q);

#pragma unroll
  for (int c = 0; c < 2; ++c) {
    const int gn = n0 + wc * 32 + c * 16 + mlane;
    const float bdv = bd[gn], buv = bu[gn];
#pragma unroll
    for (int r = 0; r < 2; ++r)
#pragma unroll
      for (int ii = 0; ii < 4; ++ii) {
        const int gm = m0 + wr * 32 + r * 16 + q * 4 + ii;
        const long idx = (long)gm * OUT_F_ + gn;
        float dp = accd[r][c][ii] + bdv;
        float up = accu[r][c][ii] + buv;
        float dgv = dp * sigf(up);
        float ugv = up * sigf(dgv);
        dg[idx] = f2bf(dgv);
        ug[idx] = f2bf(ugv);
      }
  }
}

#define ACC_ZERO(a)                             \
  _Pragma("unroll") for (int r = 0; r < 2; ++r) \
  _Pragma("unroll") for (int c = 0; c < 4; ++c) { \
    a[r][c][0] = 0.f; a[r][c][1] = 0.f; a[r][c][2] = 0.f; a[r][c][3] = 0.f; }

// ---------------- fused t-GEMM + att-GEMM + tanh + reductions (R7) -----------
__global__ __launch_bounds__(256, 2) void gemm_tatt(
    const ushort* __restrict__ dg, const ushort* __restrict__ Wt,
    const ushort* __restrict__ ug, float* __restrict__ rowlog,
    float* __restrict__ collog) {
  __shared__ ushort sm[32768];  // 64KB
  ushort* t_lds = sm;           // [32][512] shorts = 32KB
  ushort* AsT = sm + 16384;     // t-phase A stage: 32x64 = 4KB
  ushort* BsT = sm + 18432;     // t-phase B stage: 128x64 = 16KB
  ushort* BsU = sm + 16384;     // att-phase B stage: 256x64 = 32KB (aliases)
  const int i = blockIdx.x;
  const int xcd = i & 7, j = i >> 3;   // j in [0,64)
  const int b = xcd * 8 + (j >> 3);    // batch; 8 blocks of b share one XCD L2
  const int by = j & 7;                // 32-row s-strip
  const int tid = threadIdx.x, lane = tid & 63, w = tid >> 6;
  const int mlane = lane & 15, q = lane >> 4;
  const ushort* dgs = dg + (long)b * (S_ * OUT_F_) + (long)by * 32 * 512;
  const ushort* ugb = ug + (long)b * (S_ * OUT_F_);

  // ---- phase 1: t strip (waves 1x4 over cols)
#pragma unroll 1
  for (int nc = 0; nc < 4; ++nc) {
    f32x4 acc[2][2]; ACC_ZERO22(acc);
    const ushort* Bw = Wt + (long)(nc * 128) * 512;
#pragma unroll 1
    for (int k = 0; k < 8; ++k) {
      stage_tile32(dgs + k * 64, 512, AsT, w, lane);
      stage_tile<128>(Bw + k * 64, 512, BsT, w, lane);
      __syncthreads();
#pragma unroll
      for (int kk = 0; kk < 2; ++kk) {
        short8 af[2], bfr[2];
#pragma unroll
        for (int r = 0; r < 2; ++r) af[r] = frag(AsT, r * 16 + mlane, kk, q);
#pragma unroll
        for (int c = 0; c < 2; ++c)
          bfr[c] = frag(BsT, w * 32 + c * 16 + mlane, kk, q);
#pragma unroll
        for (int r = 0; r < 2; ++r)
#pragma unroll
          for (int c = 0; c < 2; ++c)
            acc[r][c] = __builtin_amdgcn_mfma_f32_16x16x32_bf16(af[r], bfr[c], acc[r][c], 0, 0, 0);
      }
      __syncthreads();
    }
#pragma unroll
    for (int r = 0; r < 2; ++r)
#pragma unroll
      for (int c = 0; c < 2; ++c)
#pragma unroll
        for (int ii = 0; ii < 4; ++ii) {
          int rr = r * 16 + q * 4 + ii;
          int col = nc * 128 + w * 32 + c * 16 + mlane;
          int cc = col >> 3;
          int ph = (cc & ~7) | ((cc & 7) ^ (rr & 7));
          t_lds[rr * 512 + ph * 8 + (col & 7)] = f2bf(acc[r][c][ii]);
        }
  }

  // ---- phase 2: att = t . ug^T (waves 1x4 over r-cols)
  f32x4 acc[2][4]; ACC_ZERO(acc);
#pragma unroll 1
  for (int k = 0; k < 8; ++k) {
    stage_tile<256>(ugb + k * 64, 512, BsU, w, lane);
    __syncthreads();
#pragma unroll
    for (int kk = 0; kk < 2; ++kk) {
      short8 af[2], bfr[4];
#pragma unroll
      for (int r = 0; r < 2; ++r) af[r] = frag512(t_lds, r * 16 + mlane, k, kk, q);
#pragma unroll
      for (int c = 0; c < 4; ++c)
        bfr[c] = frag(BsU, w * 64 + c * 16 + mlane, kk, q);
#pragma unroll
      for (int r = 0; r < 2; ++r)
#pragma unroll
        for (int c = 0; c < 4; ++c)
          acc[r][c] = __builtin_amdgcn_mfma_f32_16x16x32_bf16(af[r], bfr[c], acc[r][c], 0, 0, 0);
    }
    __syncthreads();
  }

  float rs[8], cs[4];
#pragma unroll
  for (int x = 0; x < 8; ++x) rs[x] = 0.f;
#pragma unroll
  for (int c = 0; c < 4; ++c) cs[c] = 0.f;
#pragma unroll
  for (int r = 0; r < 2; ++r)
#pragma unroll
    for (int c = 0; c < 4; ++c)
#pragma unroll
      for (int ii = 0; ii < 4; ++ii) {
        float v = tanh_safe(acc[r][c][ii]);
        rs[r * 4 + ii] += v;
        cs[c] += v;
      }
#pragma unroll
  for (int m = 1; m < 16; m <<= 1)
#pragma unroll
    for (int x = 0; x < 8; ++x) rs[x] += __shfl_xor(rs[x], m, 64);
#pragma unroll
  for (int m = 16; m < 64; m <<= 1)
#pragma unroll
    for (int c = 0; c < 4; ++c) cs[c] += __shfl_xor(cs[c], m, 64);

  float* rsum = (float*)BsU;
  if (tid < 32) rsum[tid] = 0.f;
  __syncthreads();
  if (mlane == 0) {
#pragma unroll
    for (int x = 0; x < 8; ++x)
      atomicAdd(&rsum[(x >> 2) * 16 + q * 4 + (x & 3)], rs[x]);
  }
  if (q == 0) {
#pragma unroll
    for (int c = 0; c < 4; ++c)
      atomicAdd(&collog[b * S_ + w * 64 + c * 16 + mlane], cs[c]);
  }
  __syncthreads();
  if (tid < 32) rowlog[b * S_ + by * 32 + tid] = rsum[tid];
}

// ---------------- finalize: softmax + weighted sums (vec2) -------------------
__device__ __forceinline__ float block_max(float v, float* buf, int tid) {
  buf[tid] = v; __syncthreads();
  for (int s = 128; s > 0; s >>= 1) {
    if (tid < s) buf[tid] = fmaxf(buf[tid], buf[tid + s]);
    __syncthreads();
  }
  float r = buf[0]; __syncthreads();
  return r;
}
__device__ __forceinline__ float block_sum(float v, float* buf, int tid) {
  buf[tid] = v; __syncthreads();
  for (int s = 128; s > 0; s >>= 1) {
    if (tid < s) buf[tid] = buf[tid] + buf[tid + s];
    __syncthreads();
  }
  float r = buf[0]; __syncthreads();
  return r;
}

__global__ __launch_bounds__(256) void finalize(
    const float* __restrict__ rowlog, const float* __restrict__ collog,
    const ushort* __restrict__ dg, const ushort* __restrict__ ug,
    float* __restrict__ out) {
  __shared__ float sd[S_], su[S_], buf[S_];
  const int b = blockIdx.x >> 1, half = blockIdx.x & 1;
  const int tid = threadIdx.x;

  const float rowmean = rowlog[b * S_ + tid] * (1.f / (float)S_);
  const float colmean = collog[b * S_ + tid] * (1.f / (float)S_);

  float md = block_max(rowmean, buf, tid);
  float ed = __expf(rowmean - md);
  float sds = block_sum(ed, buf, tid);
  sd[tid] = ed / sds;
  float mu = block_max(colmean, buf, tid);
  float eu = __expf(colmean - mu);
  float sus = block_sum(eu, buf, tid);
  su[tid] = eu / sus;
  __syncthreads();

  const int arr = tid >> 7;
  const int o = half * 256 + (tid & 127) * 2;
  const ushort* src = arr ? ug : dg;
  const float* sw = arr ? su : sd;
  const ushort* p = src + (long)b * (S_ * OUT_F_) + o;
  float a0 = 0.f, a1 = 0.f;
#pragma unroll 4
  for (int s = 0; s < S_; ++s) {
    ushort2 v = *(const ushort2*)(p + (long)s * OUT_F_);
    a0 += sw[s] * bf2f(v.x);
    a1 += sw[s] * bf2f(v.y);
  }
  float* ob = out + (arr ? BSZ_ * OUT_F_ : 0) + b * OUT_F_ + o;
  ob[0] = a0; ob[1] = a1;
}

extern "C" void kernel_launch(void* const* d_in, const int* in_sizes, int n_in,
                              void* d_out, int out_size, void* d_ws, size_t ws_size,
                              hipStream_t stream) {
  (void)in_sizes; (void)n_in; (void)out_size; (void)ws_size;
  const float* Xd = (const float*)d_in[0];
  const float* Xu = (const float*)d_in[1];
  const float* Wd = (const float*)d_in[2];
  const float* bd = (const float*)d_in[3];
  const float* Wu = (const float*)d_in[4];
  const float* bu = (const float*)d_in[5];
  const float* W  = (const float*)d_in[6];
  float* out = (float*)d_out;
  char* ws = (char*)d_ws;

  ushort* Xd_bf  = (ushort*)(ws + 0L);          // 33,554,432
  ushort* Xu_bf  = (ushort*)(ws + 33554432L);   // 16,777,216
  ushort* Wd_bf  = (ushort*)(ws + 50331648L);   //  1,048,576
  ushort* Wu_bf  = (ushort*)(ws + 51380224L);   //    524,288
  ushort* Wt_bf  = (ushort*)(ws + 51904512L);   //    524,288
  ushort* dg     = (ushort*)(ws + 52428800L);   // 16,777,216
  ushort* ug     = (ushort*)(ws + 69206016L);   // 16,777,216
  float*  rowlog = (float*)(ws + 85983232L);    //     65,536
  float*  collog = (float*)(ws + 86048768L);    //     65,536 (contiguous)

  prep<<<26400, 256, 0, stream>>>(Xd, Xu, Wd, Wu, W, Xd_bf, Xu_bf,
                                  Wd_bf, Wu_bf, Wt_bf, rowlog);

  dim3 blk(256);
  gemm_du<<<2048, blk, 0, stream>>>(Xd_bf, Wd_bf, bd, Xu_bf, Wu_bf, bu, dg, ug);
  gemm_tatt<<<512, blk, 0, stream>>>(dg, Wt_bf, ug, rowlog, collog);
  finalize<<<128, 256, 0, stream>>>(rowlog, collog, dg, ug, out);
}